// Round 10
// baseline (4466.612 us; speedup 1.0000x reference)
//
#include <hip/hip_runtime.h>
#include <hip/hip_bf16.h>

// LSTM trajectory predictor, Round 10: A (h-state) staged in LDS (BK=32,
// 2 buffers, 32KB); B (weights) loaded straight to registers from a
// FRAGMENT-MAJOR packed layout (one coalesced 1KB burst per wave-frag),
// double-buffered one chunk ahead. R8's plain 2-phase loop (one
// __syncthreads per chunk), paired dispatches, HF head-fold isolated.

#define HDIM 512
#define BDIM 2048
#define T_HIST 50
#define T_FUT 30

typedef __attribute__((ext_vector_type(8))) short short8;
typedef __attribute__((ext_vector_type(4))) float f32x4;

#define AS1(p) ((const __attribute__((address_space(1))) void*)(p))
#define AS3(p) ((__attribute__((address_space(3))) void*)(p))

__device__ __forceinline__ ushort f2bf(float f) {
    union { float f; unsigned u; } v; v.f = f;
    unsigned r = v.u + 0x7fff + ((v.u >> 16) & 1);   // RNE
    return (ushort)(r >> 16);
}
__device__ __forceinline__ float bf2f(ushort h) {
    union { unsigned u; float f; } v; v.u = ((unsigned)h) << 16;
    return v.f;
}

// A-region layout (128 rows x 32 k, 16B slots, 4 slots/row):
// q = row>>1, t = ((row&1)<<2)|slot, phys = q*8 + (t ^ (q&7)).  Bijective;
// frag reads (16 rows x 4 slots) hit all 32 banks conflict-free.
__device__ __forceinline__ int swz(int row, int slot) {
    int q = row >> 1;
    int t = ((row & 1) << 2) | slot;
    return q * 8 + (t ^ (q & 7));
}

// ---- weight prep: fp32 [2048][512] -> bf16 hi/lo in FRAGMENT-MAJOR layout.
// Permuted row rp = (u>>5)*128 + ((u>>4)&1)*64 + g*16 + (u&15); frag f = rp>>4.
// Packed: P[((f*16 + k32)*64 + l)*8 + e] = W[g*512+u][k32*32 + (l>>4)*8 + e]
// with lrow = l&15, rp = f*16+lrow. A wave's B-frag load for (f,k32) is then
// 64 lanes x 16B contiguous = one coalesced 1KB burst.
struct SplitSrc { const float* src[6]; };

__global__ __launch_bounds__(256) void split_weights_packed(
    SplitSrc s, ushort* __restrict__ hi, ushort* __restrict__ lo) {
    int f = blockIdx.x;               // frag 0..127
    int j = blockIdx.y;               // matrix 0..5
    // inverse of rp(g,u): g = f&3, u = ((f>>3)<<5) | (((f>>2)&1)<<4) | lrow
    const float* S = s.src[j];
    ushort* H = hi + (size_t)j * (2048 * 512) + (size_t)f * 8192;
    ushort* L = lo + (size_t)j * (2048 * 512) + (size_t)f * 8192;
    for (int gi = threadIdx.x; gi < 1024; gi += 256) {   // granule = 16B
        int k32 = gi >> 6, l = gi & 63;
        int lrow = l & 15, lk = l >> 4;
        int g = f & 3;
        int u = ((f >> 3) << 5) | (((f >> 2) & 1) << 4) | lrow;
        const float* src = S + (size_t)(g * 512 + u) * HDIM + k32 * 32 + lk * 8;
        short8 vh, vl;
        #pragma unroll
        for (int e = 0; e < 8; ++e) {
            float w = src[e];
            ushort hb = f2bf(w);
            vh[e] = (short)hb;
            vl[e] = (short)f2bf(w - bf2f(hb));
        }
        *(short8*)(H + gi * 8) = vh;
        *(short8*)(L + gi * 8) = vl;
    }
}

// ---- cell descriptor ----
struct CellDesc {
    const ushort *A1h, *A1l, *W1h, *W1l;       // W* = packed frag-major
    const ushort *A2h, *A2l, *W2h, *W2l;
    const float *x; const float *Wx;           // encoder tiny-K input path
    const float *bih, *bhh;
    const ushort *hsrc_hi, *hsrc_lo;           // decoder: h1 for head-fold (HF)
    const float *Wout, *bout; float *out_t;    // head-fold params (HF)
    float* c; ushort *hh; ushort *hl;
    int np, xs, Kx;
};

// ---- fused LSTM cell(s): blocks [0,256) run dA, [256,512) run dB ----
// Block tile 128m x 128n (32 units x 4 gates), 4 waves 2x2, wave tile 64x64
// = 4 m-frags x 4 gate-frags of mfma_f32_16x16x32_bf16, 3-product split.
template <bool HF>
__global__ __launch_bounds__(256, 2) void lstm_cells(CellDesc dA, CellDesc dB) {
    // A only: 2 buffers x (hi 4096 ushorts @0, lo 4096 @4096) = 32 KB.
    __shared__ __align__(16) ushort lds[2 * 8192];

    const CellDesc d = (blockIdx.x >> 8) ? dB : dA;

    const int tid = threadIdx.x;
    const int w = tid >> 6, l = tid & 63;
    const int wm = w >> 1, wn = w & 1;
    const int lrow = l & 15, lk = l >> 4;

    // XCD-chunked bijective swizzle within each cell's 256 blocks
    int id = blockIdx.x & 255;
    int xcd = id & 7, rr = id >> 3;
    int bx = (xcd & 3) * 4 + (rr & 3);
    int by = (xcd >> 2) * 8 + (rr >> 2);
    const int m0 = by * 128;
    const int u  = bx * 32 + wn * 16 + lrow;   // global hidden unit

    // packed-B per-lane element offsets for the 4 gate frags:
    // f_g = bx*8 + wn*4 + g; addr = f_g*8192 + k32*512 + l*8
    size_t bb[4];
    #pragma unroll
    for (int g = 0; g < 4; ++g)
        bb[g] = (size_t)(bx * 8 + wn * 4 + g) * 8192 + l * 8;

    // A staging dest/src mapping (loop-invariant)
    int dbs[2]; size_t gos[2];
    #pragma unroll
    for (int it = 0; it < 2; ++it) {
        int db = (w * 2 + it) * 64;
        int dd = db + l;
        int q = dd >> 3, tp = dd & 7;
        int tl = tp ^ (q & 7);
        int r = (q << 1) | (tl >> 2);
        int s = tl & 3;
        dbs[it] = db;
        gos[it] = (size_t)r * HDIM + s * 8;
    }

    f32x4 acc[4][4];   // [m-frag][gate]

    // ---- A staging (hi+lo) for chunk t ----
#define STAGE_A(t)                                                            \
    {                                                                         \
        int p_ = (t) >> 4;                                                    \
        int kc_ = ((t) & 15) * 32;                                            \
        const ushort* Ah_ = (p_ ? d.A2h : d.A1h) + (size_t)m0 * HDIM + kc_;   \
        const ushort* Al_ = (p_ ? d.A2l : d.A1l) + (size_t)m0 * HDIM + kc_;   \
        ushort* sb_ = &lds[((t) & 1) * 8192];                                 \
        _Pragma("unroll")                                                     \
        for (int it = 0; it < 2; ++it) {                                      \
            __builtin_amdgcn_global_load_lds(AS1(Ah_ + gos[it]),              \
                                             AS3(sb_ + dbs[it] * 8), 16, 0, 0); \
            __builtin_amdgcn_global_load_lds(AS1(Al_ + gos[it]),              \
                                             AS3(sb_ + 4096 + dbs[it] * 8), 16, 0, 0); \
        }                                                                     \
    }

    // ---- B fragment loads (coalesced 1KB bursts) for chunk t ----
#define LOADB(t, bh_, bl_)                                                    \
    {                                                                         \
        int p_ = (t) >> 4;                                                    \
        size_t ko_ = (size_t)((t) & 15) * 512;                                \
        const ushort* Bh_ = p_ ? d.W2h : d.W1h;                               \
        const ushort* Bl_ = p_ ? d.W2l : d.W1l;                               \
        _Pragma("unroll")                                                     \
        for (int g = 0; g < 4; ++g) {                                         \
            bh_[g] = *(const short8*)(Bh_ + bb[g] + ko_);                     \
            bl_[g] = *(const short8*)(Bl_ + bb[g] + ko_);                     \
        }                                                                     \
    }

    // ---- one chunk: ds_read A frags + 48 MFMAs (3-product split) ----
#define ITER(t, bhc, blc, bhn, bln)                                           \
    {                                                                         \
        __syncthreads();                                                      \
        if ((t) + 1 < nch) { STAGE_A((t) + 1); LOADB((t) + 1, bhn, bln); }    \
        ushort* base = &lds[((t) & 1) * 8192];                                \
        short8 ah[4], al[4];                                                  \
        _Pragma("unroll")                                                     \
        for (int fm = 0; fm < 4; ++fm) {                                      \
            int row_ = wm * 64 + fm * 16 + lrow;                              \
            int off_ = swz(row_, lk) * 8;                                     \
            ah[fm] = *(const short8*)(base + off_);                           \
            al[fm] = *(const short8*)(base + 4096 + off_);                    \
        }                                                                     \
        _Pragma("unroll")                                                     \
        for (int fm = 0; fm < 4; ++fm)                                        \
            _Pragma("unroll")                                                 \
            for (int g = 0; g < 4; ++g)                                       \
                acc[fm][g] = __builtin_amdgcn_mfma_f32_16x16x32_bf16(         \
                    ah[fm], bhc[g], acc[fm][g], 0, 0, 0);                     \
        _Pragma("unroll")                                                     \
        for (int fm = 0; fm < 4; ++fm)                                        \
            _Pragma("unroll")                                                 \
            for (int g = 0; g < 4; ++g)                                       \
                acc[fm][g] = __builtin_amdgcn_mfma_f32_16x16x32_bf16(         \
                    al[fm], bhc[g], acc[fm][g], 0, 0, 0);                     \
        _Pragma("unroll")                                                     \
        for (int fm = 0; fm < 4; ++fm)                                        \
            _Pragma("unroll")                                                 \
            for (int g = 0; g < 4; ++g)                                       \
                acc[fm][g] = __builtin_amdgcn_mfma_f32_16x16x32_bf16(         \
                    ah[fm], blc[g], acc[fm][g], 0, 0, 0);                     \
    }

    const int nch = d.np * 16;

    short8 bh0[4], bl0[4], bh1[4], bl1[4];
    STAGE_A(0);
    LOADB(0, bh0, bl0);

    // ---- bias init ----
    #pragma unroll
    for (int g = 0; g < 4; ++g) {
        float b = d.bih[g * HDIM + u] + d.bhh[g * HDIM + u];
        f32x4 bv = {b, b, b, b};
        #pragma unroll
        for (int fm = 0; fm < 4; ++fm) acc[fm][g] = bv;
    }

    // ---- encoder tiny-K x path (K=5, reads history) ----
    if (d.Kx > 0) {
        for (int kx = 0; kx < d.Kx; ++kx) {
            float wv[4];
            #pragma unroll
            for (int g = 0; g < 4; ++g) wv[g] = d.Wx[(size_t)(g * HDIM + u) * d.Kx + kx];
            #pragma unroll
            for (int fm = 0; fm < 4; ++fm)
                #pragma unroll
                for (int r = 0; r < 4; ++r) {
                    int m = m0 + wm * 64 + fm * 16 + lk * 4 + r;
                    float xv = d.x[(size_t)m * d.xs + kx];
                    #pragma unroll
                    for (int g = 0; g < 4; ++g) acc[fm][g][r] += xv * wv[g];
                }
        }
    }

    // ---- decoder head-fold (HF only): x = h1_prev @ Wout^T + bout,
    // write out[t-1], then add x @ Wx^T into acc ----
    if constexpr (HF) {
        __shared__ float xlds[128][2];
        if (d.hsrc_hi) {
            int row = tid >> 1, half = tid & 1;
            const ushort* hh = d.hsrc_hi + (size_t)(m0 + row) * HDIM + half * 256;
            const ushort* hl = d.hsrc_lo + (size_t)(m0 + row) * HDIM + half * 256;
            float s0 = 0.f, s1 = 0.f;
            #pragma unroll 4
            for (int j = 0; j < 32; ++j) {
                short8 a = *(const short8*)(hh + j * 8);
                short8 b = *(const short8*)(hl + j * 8);
                #pragma unroll
                for (int e = 0; e < 8; ++e) {
                    float hv = bf2f((ushort)a[e]) + bf2f((ushort)b[e]);
                    int k = half * 256 + j * 8 + e;
                    s0 += hv * d.Wout[k];
                    s1 += hv * d.Wout[HDIM + k];
                }
            }
            s0 += __shfl_xor(s0, 1);
            s1 += __shfl_xor(s1, 1);
            float x0 = s0 + d.bout[0], x1 = s1 + d.bout[1];
            if (half == 0) {
                xlds[row][0] = x0; xlds[row][1] = x1;
                if (bx == 0 && d.out_t) {
                    d.out_t[(size_t)(m0 + row) * (T_FUT * 2) + 0] = x0;
                    d.out_t[(size_t)(m0 + row) * (T_FUT * 2) + 1] = x1;
                }
            }
            __syncthreads();
            #pragma unroll
            for (int g = 0; g < 4; ++g) {
                float w0 = d.Wx[(size_t)(g * HDIM + u) * 2 + 0];
                float w1 = d.Wx[(size_t)(g * HDIM + u) * 2 + 1];
                #pragma unroll
                for (int fm = 0; fm < 4; ++fm)
                    #pragma unroll
                    for (int r = 0; r < 4; ++r) {
                        int ml = wm * 64 + fm * 16 + lk * 4 + r;
                        acc[fm][g][r] += xlds[ml][0] * w0 + xlds[ml][1] * w1;
                    }
            }
        }
    }

    // ---- main loop (register rotation, nch always even) ----
    for (int t = 0; t < nch; t += 2) {
        ITER(t, bh0, bl0, bh1, bl1);
        ITER(t + 1, bh1, bl1, bh0, bl0);
    }

    // ---- epilogue: gates + state update. Thread owns 16 rows x 1 unit. ----
    #pragma unroll
    for (int fm = 0; fm < 4; ++fm)
        #pragma unroll
        for (int r = 0; r < 4; ++r) {
            int m = m0 + wm * 64 + fm * 16 + lk * 4 + r;
            size_t idx = (size_t)m * HDIM + u;
            float zi = acc[fm][0][r], zf = acc[fm][1][r];
            float zg = acc[fm][2][r], zo = acc[fm][3][r];
            float ig = 1.f / (1.f + __expf(-zi));
            float fg = 1.f / (1.f + __expf(-zf));
            float gg = 2.f / (1.f + __expf(-2.f * zg)) - 1.f;
            float og = 1.f / (1.f + __expf(-zo));
            float cn = fg * d.c[idx] + ig * gg;
            float hn = og * (2.f / (1.f + __expf(-2.f * cn)) - 1.f);
            d.c[idx] = cn;
            ushort hb = f2bf(hn);
            d.hh[idx] = hb;
            d.hl[idx] = f2bf(hn - bf2f(hb));
        }
#undef STAGE_A
#undef LOADB
#undef ITER
}

// ---- final output for t=29 (no following D0 to fold into) ----
__global__ __launch_bounds__(256) void head_kernel(
    const ushort* __restrict__ hhi, const ushort* __restrict__ hlo,
    const float* __restrict__ Wout, const float* __restrict__ bout,
    float* __restrict__ out, int t)
{
    int wave = (blockIdx.x * 256 + threadIdx.x) >> 6;
    int lane = threadIdx.x & 63;
    const ushort* hr = hhi + (size_t)wave * HDIM;
    const ushort* lr = hlo + (size_t)wave * HDIM;
    float s0 = 0.f, s1 = 0.f;
    #pragma unroll
    for (int k = lane; k < HDIM; k += 64) {
        float hv = bf2f(hr[k]) + bf2f(lr[k]);
        s0 += hv * Wout[k];
        s1 += hv * Wout[HDIM + k];
    }
    #pragma unroll
    for (int off = 32; off > 0; off >>= 1) {
        s0 += __shfl_down(s0, off);
        s1 += __shfl_down(s1, off);
    }
    if (lane == 0) {
        out[(size_t)wave * (T_FUT * 2) + t * 2 + 0] = s0 + bout[0];
        out[(size_t)wave * (T_FUT * 2) + t * 2 + 1] = s1 + bout[1];
    }
}

extern "C" void kernel_launch(void* const* d_in, const int* in_sizes, int n_in,
                              void* d_out, int out_size, void* d_ws, size_t ws_size,
                              hipStream_t stream) {
    const float* history = (const float*)d_in[0];
    const float* eWih0 = (const float*)d_in[2];
    const float* eWhh0 = (const float*)d_in[3];
    const float* ebih0 = (const float*)d_in[4];
    const float* ebhh0 = (const float*)d_in[5];
    const float* eWih1 = (const float*)d_in[6];
    const float* eWhh1 = (const float*)d_in[7];
    const float* ebih1 = (const float*)d_in[8];
    const float* ebhh1 = (const float*)d_in[9];
    const float* dWih0 = (const float*)d_in[10];
    const float* dWhh0 = (const float*)d_in[11];
    const float* dbih0 = (const float*)d_in[12];
    const float* dbhh0 = (const float*)d_in[13];
    const float* dWih1 = (const float*)d_in[14];
    const float* dWhh1 = (const float*)d_in[15];
    const float* dbih1 = (const float*)d_in[16];
    const float* dbhh1 = (const float*)d_in[17];
    const float* outW  = (const float*)d_in[18];
    const float* outb  = (const float*)d_in[19];
    float* out = (float*)d_out;

    // ---- workspace layout ----
    const size_t M = (size_t)2048 * 512;
    ushort* whi = (ushort*)d_ws;           // 6 packed-hi weight matrices
    ushort* wlo = whi + 6 * M;             // 6 packed-lo
    ushort* hb  = wlo + 6 * M;             // 8 h buffers (hi/lo x 2 layers x dbuf)
    float*  c0  = (float*)(hb + 8 * M);
    float*  c1  = c0 + M;

    ushort* h0a_hi = hb + 0 * M; ushort* h0a_lo = hb + 1 * M;
    ushort* h0b_hi = hb + 2 * M; ushort* h0b_lo = hb + 3 * M;
    ushort* h1a_hi = hb + 4 * M; ushort* h1a_lo = hb + 5 * M;
    ushort* h1b_hi = hb + 6 * M; ushort* h1b_lo = hb + 7 * M;

    hipMemsetAsync(h0a_hi, 0, 2 * M * sizeof(ushort), stream);
    hipMemsetAsync(h1a_hi, 0, 2 * M * sizeof(ushort), stream);
    hipMemsetAsync(c0, 0, 2 * M * sizeof(float), stream);

    SplitSrc ss;
    ss.src[0] = eWhh0; ss.src[1] = eWih1; ss.src[2] = eWhh1;
    ss.src[3] = dWhh0; ss.src[4] = dWih1; ss.src[5] = dWhh1;
    split_weights_packed<<<dim3(128, 6), 256, 0, stream>>>(ss, whi, wlo);

    #define WHI(j) (whi + (size_t)(j) * M)
    #define WLO(j) (wlo + (size_t)(j) * M)

    auto H0R_HI = [&](int s){ return (s & 1) ? h0b_hi : h0a_hi; };
    auto H0R_LO = [&](int s){ return (s & 1) ? h0b_lo : h0a_lo; };
    auto H0W_HI = [&](int s){ return (s & 1) ? h0a_hi : h0b_hi; };
    auto H0W_LO = [&](int s){ return (s & 1) ? h0a_lo : h0b_lo; };
    auto H1R_HI = [&](int s){ return (s & 1) ? h1b_hi : h1a_hi; };
    auto H1R_LO = [&](int s){ return (s & 1) ? h1b_lo : h1a_lo; };
    auto H1W_HI = [&](int s){ return (s & 1) ? h1a_hi : h1b_hi; };
    auto H1W_LO = [&](int s){ return (s & 1) ? h1a_lo : h1b_lo; };

    auto mkL0enc = [&](int s) {
        CellDesc d{};
        d.A1h = H0R_HI(s); d.A1l = H0R_LO(s); d.W1h = WHI(0); d.W1l = WLO(0);
        d.np = 1; d.x = history + s * 5; d.xs = T_HIST * 5; d.Kx = 5; d.Wx = eWih0;
        d.bih = ebih0; d.bhh = ebhh0; d.c = c0; d.hh = H0W_HI(s); d.hl = H0W_LO(s);
        return d;
    };
    auto mkL1enc = [&](int s) {
        CellDesc d{};
        d.A1h = H0W_HI(s); d.A1l = H0W_LO(s); d.W1h = WHI(1); d.W1l = WLO(1);
        d.A2h = H1R_HI(s); d.A2l = H1R_LO(s); d.W2h = WHI(2); d.W2l = WLO(2);
        d.np = 2; d.Kx = 0; d.xs = 0;
        d.bih = ebih1; d.bhh = ebhh1; d.c = c1; d.hh = H1W_HI(s); d.hl = H1W_LO(s);
        return d;
    };
    // decoder layer-0: head folded in (x from h1(s-1)); s==T_HIST -> x=0
    auto mkD0 = [&](int s) {
        CellDesc d{};
        d.A1h = H0R_HI(s); d.A1l = H0R_LO(s); d.W1h = WHI(3); d.W1l = WLO(3);
        d.np = 1; d.Kx = 0; d.xs = 0; d.Wx = dWih0;
        if (s > T_HIST) {
            d.hsrc_hi = H1W_HI(s - 1); d.hsrc_lo = H1W_LO(s - 1);
            d.Wout = outW; d.bout = outb;
            d.out_t = out + (size_t)(s - T_HIST - 1) * 2;
        }
        d.bih = dbih0; d.bhh = dbhh0; d.c = c0; d.hh = H0W_HI(s); d.hl = H0W_LO(s);
        return d;
    };
    auto mkD1 = [&](int s) {
        CellDesc d{};
        d.A1h = H0W_HI(s); d.A1l = H0W_LO(s); d.W1h = WHI(4); d.W1l = WLO(4);
        d.A2h = H1R_HI(s); d.A2l = H1R_LO(s); d.W2h = WHI(5); d.W2l = WLO(5);
        d.np = 2; d.Kx = 0; d.xs = 0;
        d.bih = dbih1; d.bhh = dbhh1; d.c = c1; d.hh = H1W_HI(s); d.hl = H1W_LO(s);
        return d;
    };

    dim3 blk(256);

    // encoder step 0, layer 0 alone
    {
        CellDesc d = mkL0enc(0);
        lstm_cells<false><<<256, blk, 0, stream>>>(d, d);
    }
    // paired: [L1(s) || L0(s+1)]; last pair feeds the decoder (D0(50), x=0)
    for (int s = 0; s < T_HIST; ++s) {
        CellDesc dL1 = mkL1enc(s);
        CellDesc dNx = (s + 1 < T_HIST) ? mkL0enc(s + 1) : mkD0(T_HIST);
        lstm_cells<false><<<512, blk, 0, stream>>>(dL1, dNx);
    }
    // decoder: D1(s) -> D0(s+1) (head folded into D0's prologue, HF variant)
    for (int s = T_HIST; s < T_HIST + T_FUT; ++s) {
        CellDesc d1 = mkD1(s);
        lstm_cells<false><<<256, blk, 0, stream>>>(d1, d1);
        if (s + 1 < T_HIST + T_FUT) {
            CellDesc d0 = mkD0(s + 1);
            lstm_cells<true><<<256, blk, 0, stream>>>(d0, d0);
        }
    }
    // final prediction t = 29
    head_kernel<<<512, blk, 0, stream>>>(
        H1W_HI(T_HIST + T_FUT - 1), H1W_LO(T_HIST + T_FUT - 1),
        outW, outb, out, T_FUT - 1);
    #undef WHI
    #undef WLO
}

// Round 11
// 4358.170 us; speedup vs baseline: 1.0249x; 1.0249x over previous
//
#include <hip/hip_runtime.h>
#include <hip/hip_bf16.h>

// LSTM trajectory predictor, Round 11: R5/R8 hot path exactly (A+B staged in
// LDS row-major-permuted, BK=32, 2 buffers, 2 blocks/CU, one __syncthreads
// per chunk) + head-fold in decoder D0 with COALESCED h1 reads (wave-per-32-
// rows, contiguous 1KB bursts). HF isolated via template so encoder keeps
// 88 VGPR.

#define HDIM 512
#define BDIM 2048
#define T_HIST 50
#define T_FUT 30

typedef __attribute__((ext_vector_type(8))) short short8;
typedef __attribute__((ext_vector_type(4))) float f32x4;

#define AS1(p) ((const __attribute__((address_space(1))) void*)(p))
#define AS3(p) ((__attribute__((address_space(3))) void*)(p))

__device__ __forceinline__ ushort f2bf(float f) {
    union { float f; unsigned u; } v; v.f = f;
    unsigned r = v.u + 0x7fff + ((v.u >> 16) & 1);   // RNE
    return (ushort)(r >> 16);
}
__device__ __forceinline__ float bf2f(ushort h) {
    union { unsigned u; float f; } v; v.u = ((unsigned)h) << 16;
    return v.f;
}

// Region layout (128 rows x 32 k, 16B slots, 4 slots/row):
// q = row>>1, t = ((row&1)<<2)|slot, phys = q*8 + (t ^ (q&7)).  Bijective;
// frag reads (16 rows x 4 slots) hit all 32 banks conflict-free.
__device__ __forceinline__ int swz(int row, int slot) {
    int q = row >> 1;
    int t = ((row & 1) << 2) | slot;
    return q * 8 + (t ^ (q & 7));
}

// ---- weight prep: fp32 [2048][512] -> bf16 hi/lo, rows permuted so a
// block's 128 rows = 32 units x 4 gates.
// input row = g*512 + u ; rp = (u>>5)*128 + ((u>>4)&1)*64 + g*16 + (u&15)
struct SplitSrc { const float* src[6]; };

__global__ __launch_bounds__(256) void split_weights(SplitSrc s, ushort* __restrict__ hi,
                                                     ushort* __restrict__ lo) {
    int row = blockIdx.x;             // g*512 + u
    int j = blockIdx.y;               // matrix index
    int g = row >> 9, u = row & 511;
    int rp = (u >> 5) * 128 + ((u >> 4) & 1) * 64 + g * 16 + (u & 15);
    const float* S = s.src[j] + (size_t)row * HDIM;
    ushort* H = hi + ((size_t)j * 2048 + rp) * HDIM;
    ushort* L = lo + ((size_t)j * 2048 + rp) * HDIM;
    for (int k = threadIdx.x; k < HDIM; k += 256) {
        float w = S[k];
        ushort hb = f2bf(w);
        H[k] = hb;
        L[k] = f2bf(w - bf2f(hb));
    }
}

// ---- cell descriptor ----
struct CellDesc {
    const ushort *A1h, *A1l, *W1h, *W1l;
    const ushort *A2h, *A2l, *W2h, *W2l;
    const float *x; const float *Wx;           // encoder tiny-K input path
    const float *bih, *bhh;
    const ushort *hsrc_hi, *hsrc_lo;           // decoder: h1 for head-fold (HF)
    const float *Wout, *bout; float *out_t;    // head-fold params (HF)
    float* c; ushort *hh; ushort *hl;
    int np, xs, Kx;
};

// ---- fused LSTM cell(s): blocks [0,256) run dA, [256,512) run dB ----
// Block tile 128m x 128n (32 units x 4 gates), 4 waves 2x2, wave tile 64x64
// = 4 m-frags x 4 gate-frags of mfma_f32_16x16x32_bf16, 3-product split.
template <bool HF>
__global__ __launch_bounds__(256, 2) void lstm_cells(CellDesc dA, CellDesc dB) {
    // 2 buffers x 32KB. Regions (ushort offs): A_hi @0, A_lo @4096,
    // B_hi @8192, B_lo @12288; each 512 slots x 16B, swizzled.
    __shared__ __align__(16) ushort lds[2 * 16384];

    const CellDesc d = (blockIdx.x >> 8) ? dB : dA;

    const int tid = threadIdx.x;
    const int w = tid >> 6, l = tid & 63;
    const int wm = w >> 1, wn = w & 1;
    const int lrow = l & 15, lk = l >> 4;

    // XCD-chunked bijective swizzle within each cell's 256 blocks
    int id = blockIdx.x & 255;
    int xcd = id & 7, rr = id >> 3;
    int bx = (xcd & 3) * 4 + (rr & 3);
    int by = (xcd >> 2) * 8 + (rr >> 2);
    const int m0 = by * 128;
    const int n0 = bx * 128;
    const int u  = bx * 32 + wn * 16 + lrow;   // global hidden unit

    f32x4 acc[4][4];   // [m-frag][gate]

    // ---- staging: 16 global_load_lds (16B) per wave per chunk ----
    auto STAGE = [&](int t) {
        int buf = t & 1;
        int p = t >> 4;                 // 16 chunks per (A,W) pair
        int kc = (t & 15) * 32;
        const ushort* Ah = p ? d.A2h : d.A1h;
        const ushort* Al = p ? d.A2l : d.A1l;
        const ushort* Bh = p ? d.W2h : d.W1h;
        const ushort* Bl = p ? d.W2l : d.W1l;
        ushort* base = &lds[buf * 16384];
        #pragma unroll
        for (int it = 0; it < 2; ++it) {
            int db = (w * 2 + it) * 64;       // wave-uniform dest slot base
            int dd = db + l;                  // this lane's dest slot
            int q = dd >> 3, tp = dd & 7;
            int tl = tp ^ (q & 7);            // inverse swizzle -> logical
            int r = (q << 1) | (tl >> 2);
            int s = tl & 3;
            size_t go = (size_t)r * HDIM + kc + s * 8;
            __builtin_amdgcn_global_load_lds(AS1(Ah + (size_t)m0 * HDIM + go),
                                             AS3(base + db * 8), 16, 0, 0);
            __builtin_amdgcn_global_load_lds(AS1(Al + (size_t)m0 * HDIM + go),
                                             AS3(base + 4096 + db * 8), 16, 0, 0);
            __builtin_amdgcn_global_load_lds(AS1(Bh + (size_t)n0 * HDIM + go),
                                             AS3(base + 8192 + db * 8), 16, 0, 0);
            __builtin_amdgcn_global_load_lds(AS1(Bl + (size_t)n0 * HDIM + go),
                                             AS3(base + 12288 + db * 8), 16, 0, 0);
        }
    };

    const int nch = d.np * 16;
    STAGE(0);

    // ---- bias init ----
    #pragma unroll
    for (int g = 0; g < 4; ++g) {
        float b = d.bih[g * HDIM + u] + d.bhh[g * HDIM + u];
        f32x4 bv = {b, b, b, b};
        #pragma unroll
        for (int fm = 0; fm < 4; ++fm) acc[fm][g] = bv;
    }

    // ---- encoder tiny-K x path (K=5, reads history) ----
    if (d.Kx > 0) {
        for (int kx = 0; kx < d.Kx; ++kx) {
            float wv[4];
            #pragma unroll
            for (int g = 0; g < 4; ++g) wv[g] = d.Wx[(size_t)(g * HDIM + u) * d.Kx + kx];
            #pragma unroll
            for (int fm = 0; fm < 4; ++fm)
                #pragma unroll
                for (int r = 0; r < 4; ++r) {
                    int m = m0 + wm * 64 + fm * 16 + lk * 4 + r;
                    float xv = d.x[(size_t)m * d.xs + kx];
                    #pragma unroll
                    for (int g = 0; g < 4; ++g) acc[fm][g][r] += xv * wv[g];
                }
        }
    }

    // ---- decoder head-fold (HF only): x = h1_prev @ Wout^T + bout,
    // write out[t-1], then add x @ Wx^T into acc. COALESCED: wave w owns
    // rows w*32..w*32+31; per row the 64 lanes read contiguous 1KB (hi)
    // + 1KB (lo): lane k-slice = l*8..l*8+7. Wout slice hoisted. ----
    if constexpr (HF) {
        __shared__ float xlds[128][2];
        if (d.hsrc_hi) {
            const int kbase = l * 8;
            float w0[8], w1[8];
            #pragma unroll
            for (int e = 0; e < 8; ++e) {
                w0[e] = d.Wout[kbase + e];
                w1[e] = d.Wout[HDIM + kbase + e];
            }
            #pragma unroll 4
            for (int i = 0; i < 32; ++i) {
                int row = w * 32 + i;
                const ushort* hh = d.hsrc_hi + (size_t)(m0 + row) * HDIM + kbase;
                const ushort* hl = d.hsrc_lo + (size_t)(m0 + row) * HDIM + kbase;
                short8 a = *(const short8*)hh;
                short8 b = *(const short8*)hl;
                float s0 = 0.f, s1 = 0.f;
                #pragma unroll
                for (int e = 0; e < 8; ++e) {
                    float hv = bf2f((ushort)a[e]) + bf2f((ushort)b[e]);
                    s0 += hv * w0[e];
                    s1 += hv * w1[e];
                }
                #pragma unroll
                for (int off = 32; off > 0; off >>= 1) {
                    s0 += __shfl_down(s0, off);
                    s1 += __shfl_down(s1, off);
                }
                if (l == 0) {
                    float x0 = s0 + d.bout[0], x1 = s1 + d.bout[1];
                    xlds[row][0] = x0; xlds[row][1] = x1;
                    if (bx == 0 && d.out_t) {
                        d.out_t[(size_t)(m0 + row) * (T_FUT * 2) + 0] = x0;
                        d.out_t[(size_t)(m0 + row) * (T_FUT * 2) + 1] = x1;
                    }
                }
            }
            __syncthreads();
            #pragma unroll
            for (int g = 0; g < 4; ++g) {
                float wx0 = d.Wx[(size_t)(g * HDIM + u) * 2 + 0];
                float wx1 = d.Wx[(size_t)(g * HDIM + u) * 2 + 1];
                #pragma unroll
                for (int fm = 0; fm < 4; ++fm)
                    #pragma unroll
                    for (int r = 0; r < 4; ++r) {
                        int ml = wm * 64 + fm * 16 + lk * 4 + r;
                        acc[fm][g][r] += xlds[ml][0] * wx0 + xlds[ml][1] * wx1;
                    }
            }
        }
    }

    // ---- main loop: one __syncthreads per chunk; stage t+1 while computing t.
    // Cross-block TLP (2 blocks/CU) hides the drain. (R5 body, verbatim.) ----
    for (int t = 0; t < nch; ++t) {
        __syncthreads();                 // STAGE(t) visible; prev reads done
        if (t + 1 < nch) STAGE(t + 1);
        ushort* base = &lds[(t & 1) * 16384];
        short8 ah[4], al[4], bh[4], bl[4];
        #pragma unroll
        for (int fm = 0; fm < 4; ++fm) {
            int row = wm * 64 + fm * 16 + lrow;
            int off = swz(row, lk) * 8;
            ah[fm] = *(const short8*)(base + off);
            al[fm] = *(const short8*)(base + 4096 + off);
        }
        #pragma unroll
        for (int g = 0; g < 4; ++g) {
            int row = wn * 64 + g * 16 + lrow;
            int off = swz(row, lk) * 8;
            bh[g] = *(const short8*)(base + 8192 + off);
            bl[g] = *(const short8*)(base + 12288 + off);
        }
        #pragma unroll
        for (int fm = 0; fm < 4; ++fm)
            #pragma unroll
            for (int g = 0; g < 4; ++g)
                acc[fm][g] = __builtin_amdgcn_mfma_f32_16x16x32_bf16(
                    ah[fm], bh[g], acc[fm][g], 0, 0, 0);
        #pragma unroll
        for (int fm = 0; fm < 4; ++fm)
            #pragma unroll
            for (int g = 0; g < 4; ++g)
                acc[fm][g] = __builtin_amdgcn_mfma_f32_16x16x32_bf16(
                    al[fm], bh[g], acc[fm][g], 0, 0, 0);
        #pragma unroll
        for (int fm = 0; fm < 4; ++fm)
            #pragma unroll
            for (int g = 0; g < 4; ++g)
                acc[fm][g] = __builtin_amdgcn_mfma_f32_16x16x32_bf16(
                    ah[fm], bl[g], acc[fm][g], 0, 0, 0);
    }

    // ---- epilogue: gates + state update. Thread owns 16 rows x 1 unit. ----
    #pragma unroll
    for (int fm = 0; fm < 4; ++fm)
        #pragma unroll
        for (int r = 0; r < 4; ++r) {
            int m = m0 + wm * 64 + fm * 16 + lk * 4 + r;
            size_t idx = (size_t)m * HDIM + u;
            float zi = acc[fm][0][r], zf = acc[fm][1][r];
            float zg = acc[fm][2][r], zo = acc[fm][3][r];
            float ig = 1.f / (1.f + __expf(-zi));
            float fg = 1.f / (1.f + __expf(-zf));
            float gg = 2.f / (1.f + __expf(-2.f * zg)) - 1.f;
            float og = 1.f / (1.f + __expf(-zo));
            float cn = fg * d.c[idx] + ig * gg;
            float hn = og * (2.f / (1.f + __expf(-2.f * cn)) - 1.f);
            d.c[idx] = cn;
            ushort hb = f2bf(hn);
            d.hh[idx] = hb;
            d.hl[idx] = f2bf(hn - bf2f(hb));
        }
}

// ---- final output for t=29 (no following D0 to fold into) ----
__global__ __launch_bounds__(256) void head_kernel(
    const ushort* __restrict__ hhi, const ushort* __restrict__ hlo,
    const float* __restrict__ Wout, const float* __restrict__ bout,
    float* __restrict__ out, int t)
{
    int wave = (blockIdx.x * 256 + threadIdx.x) >> 6;
    int lane = threadIdx.x & 63;
    const ushort* hr = hhi + (size_t)wave * HDIM;
    const ushort* lr = hlo + (size_t)wave * HDIM;
    float s0 = 0.f, s1 = 0.f;
    #pragma unroll
    for (int k = lane; k < HDIM; k += 64) {
        float hv = bf2f(hr[k]) + bf2f(lr[k]);
        s0 += hv * Wout[k];
        s1 += hv * Wout[HDIM + k];
    }
    #pragma unroll
    for (int off = 32; off > 0; off >>= 1) {
        s0 += __shfl_down(s0, off);
        s1 += __shfl_down(s1, off);
    }
    if (lane == 0) {
        out[(size_t)wave * (T_FUT * 2) + t * 2 + 0] = s0 + bout[0];
        out[(size_t)wave * (T_FUT * 2) + t * 2 + 1] = s1 + bout[1];
    }
}

extern "C" void kernel_launch(void* const* d_in, const int* in_sizes, int n_in,
                              void* d_out, int out_size, void* d_ws, size_t ws_size,
                              hipStream_t stream) {
    const float* history = (const float*)d_in[0];
    const float* eWih0 = (const float*)d_in[2];
    const float* eWhh0 = (const float*)d_in[3];
    const float* ebih0 = (const float*)d_in[4];
    const float* ebhh0 = (const float*)d_in[5];
    const float* eWih1 = (const float*)d_in[6];
    const float* eWhh1 = (const float*)d_in[7];
    const float* ebih1 = (const float*)d_in[8];
    const float* ebhh1 = (const float*)d_in[9];
    const float* dWih0 = (const float*)d_in[10];
    const float* dWhh0 = (const float*)d_in[11];
    const float* dbih0 = (const float*)d_in[12];
    const float* dbhh0 = (const float*)d_in[13];
    const float* dWih1 = (const float*)d_in[14];
    const float* dWhh1 = (const float*)d_in[15];
    const float* dbih1 = (const float*)d_in[16];
    const float* dbhh1 = (const float*)d_in[17];
    const float* outW  = (const float*)d_in[18];
    const float* outb  = (const float*)d_in[19];
    float* out = (float*)d_out;

    // ---- workspace layout ----
    const size_t M = (size_t)2048 * 512;
    ushort* whi = (ushort*)d_ws;           // 6 split-hi weight matrices
    ushort* wlo = whi + 6 * M;             // 6 split-lo
    ushort* hb  = wlo + 6 * M;             // 8 h buffers (hi/lo x 2 layers x dbuf)
    float*  c0  = (float*)(hb + 8 * M);
    float*  c1  = c0 + M;

    ushort* h0a_hi = hb + 0 * M; ushort* h0a_lo = hb + 1 * M;
    ushort* h0b_hi = hb + 2 * M; ushort* h0b_lo = hb + 3 * M;
    ushort* h1a_hi = hb + 4 * M; ushort* h1a_lo = hb + 5 * M;
    ushort* h1b_hi = hb + 6 * M; ushort* h1b_lo = hb + 7 * M;

    hipMemsetAsync(h0a_hi, 0, 2 * M * sizeof(ushort), stream);
    hipMemsetAsync(h1a_hi, 0, 2 * M * sizeof(ushort), stream);
    hipMemsetAsync(c0, 0, 2 * M * sizeof(float), stream);

    SplitSrc ss;
    ss.src[0] = eWhh0; ss.src[1] = eWih1; ss.src[2] = eWhh1;
    ss.src[3] = dWhh0; ss.src[4] = dWih1; ss.src[5] = dWhh1;
    split_weights<<<dim3(2048, 6), 256, 0, stream>>>(ss, whi, wlo);

    #define WHI(j) (whi + (size_t)(j) * M)
    #define WLO(j) (wlo + (size_t)(j) * M)

    auto H0R_HI = [&](int s){ return (s & 1) ? h0b_hi : h0a_hi; };
    auto H0R_LO = [&](int s){ return (s & 1) ? h0b_lo : h0a_lo; };
    auto H0W_HI = [&](int s){ return (s & 1) ? h0a_hi : h0b_hi; };
    auto H0W_LO = [&](int s){ return (s & 1) ? h0a_lo : h0b_lo; };
    auto H1R_HI = [&](int s){ return (s & 1) ? h1b_hi : h1a_hi; };
    auto H1R_LO = [&](int s){ return (s & 1) ? h1b_lo : h1a_lo; };
    auto H1W_HI = [&](int s){ return (s & 1) ? h1a_hi : h1b_hi; };
    auto H1W_LO = [&](int s){ return (s & 1) ? h1a_lo : h1b_lo; };

    auto mkL0enc = [&](int s) {
        CellDesc d{};
        d.A1h = H0R_HI(s); d.A1l = H0R_LO(s); d.W1h = WHI(0); d.W1l = WLO(0);
        d.np = 1; d.x = history + s * 5; d.xs = T_HIST * 5; d.Kx = 5; d.Wx = eWih0;
        d.bih = ebih0; d.bhh = ebhh0; d.c = c0; d.hh = H0W_HI(s); d.hl = H0W_LO(s);
        return d;
    };
    auto mkL1enc = [&](int s) {
        CellDesc d{};
        d.A1h = H0W_HI(s); d.A1l = H0W_LO(s); d.W1h = WHI(1); d.W1l = WLO(1);
        d.A2h = H1R_HI(s); d.A2l = H1R_LO(s); d.W2h = WHI(2); d.W2l = WLO(2);
        d.np = 2; d.Kx = 0; d.xs = 0;
        d.bih = ebih1; d.bhh = ebhh1; d.c = c1; d.hh = H1W_HI(s); d.hl = H1W_LO(s);
        return d;
    };
    // decoder layer-0: head folded in (x from h1(s-1)); s==T_HIST -> x=0
    auto mkD0 = [&](int s) {
        CellDesc d{};
        d.A1h = H0R_HI(s); d.A1l = H0R_LO(s); d.W1h = WHI(3); d.W1l = WLO(3);
        d.np = 1; d.Kx = 0; d.xs = 0; d.Wx = dWih0;
        if (s > T_HIST) {
            d.hsrc_hi = H1W_HI(s - 1); d.hsrc_lo = H1W_LO(s - 1);
            d.Wout = outW; d.bout = outb;
            d.out_t = out + (size_t)(s - T_HIST - 1) * 2;
        }
        d.bih = dbih0; d.bhh = dbhh0; d.c = c0; d.hh = H0W_HI(s); d.hl = H0W_LO(s);
        return d;
    };
    auto mkD1 = [&](int s) {
        CellDesc d{};
        d.A1h = H0W_HI(s); d.A1l = H0W_LO(s); d.W1h = WHI(4); d.W1l = WLO(4);
        d.A2h = H1R_HI(s); d.A2l = H1R_LO(s); d.W2h = WHI(5); d.W2l = WLO(5);
        d.np = 2; d.Kx = 0; d.xs = 0;
        d.bih = dbih1; d.bhh = dbhh1; d.c = c1; d.hh = H1W_HI(s); d.hl = H1W_LO(s);
        return d;
    };

    dim3 blk(256);

    // encoder step 0, layer 0 alone
    {
        CellDesc d = mkL0enc(0);
        lstm_cells<false><<<256, blk, 0, stream>>>(d, d);
    }
    // paired: [L1(s) || L0(s+1)]; last pair feeds the decoder (D0(50), x=0)
    for (int s = 0; s < T_HIST; ++s) {
        CellDesc dL1 = mkL1enc(s);
        CellDesc dNx = (s + 1 < T_HIST) ? mkL0enc(s + 1) : mkD0(T_HIST);
        lstm_cells<false><<<512, blk, 0, stream>>>(dL1, dNx);
    }
    // decoder: D1(s) -> D0(s+1) (head folded into D0's prologue, HF variant)
    for (int s = T_HIST; s < T_HIST + T_FUT; ++s) {
        CellDesc d1 = mkD1(s);
        lstm_cells<false><<<256, blk, 0, stream>>>(d1, d1);
        if (s + 1 < T_HIST + T_FUT) {
            CellDesc d0 = mkD0(s + 1);
            lstm_cells<true><<<256, blk, 0, stream>>>(d0, d0);
        }
    }
    // final prediction t = 29
    head_kernel<<<512, blk, 0, stream>>>(
        H1W_HI(T_HIST + T_FUT - 1), H1W_LO(T_HIST + T_FUT - 1),
        outW, outb, out, T_FUT - 1);
    #undef WHI
    #undef WLO
}

// Round 12
// 3772.179 us; speedup vs baseline: 1.1841x; 1.1553x over previous
//
#include <hip/hip_runtime.h>
#include <hip/hip_bf16.h>

// LSTM trajectory predictor, Round 12: consolidation revert to the measured
// best (R5, 3771 us). bf16 hi/lo split MFMA cells; BK=32, 2 LDS buffers
// (64KB -> 2 blocks/CU), plain 2-phase loop (one __syncthreads per chunk),
// PAIRED dispatches [L1(s) || L0(s+1)], separate parallel head kernel.
// Post-R5 variants all null/negative: B-from-global (R6/R10), setprio (R7),
// head-fold (R8/R11), counted vmcnt (R9 - TLP already hides the drain).

#define HDIM 512
#define BDIM 2048
#define T_HIST 50
#define T_FUT 30

typedef __attribute__((ext_vector_type(8))) short short8;
typedef __attribute__((ext_vector_type(4))) float f32x4;

#define AS1(p) ((const __attribute__((address_space(1))) void*)(p))
#define AS3(p) ((__attribute__((address_space(3))) void*)(p))

__device__ __forceinline__ ushort f2bf(float f) {
    union { float f; unsigned u; } v; v.f = f;
    unsigned r = v.u + 0x7fff + ((v.u >> 16) & 1);   // RNE
    return (ushort)(r >> 16);
}
__device__ __forceinline__ float bf2f(ushort h) {
    union { unsigned u; float f; } v; v.u = ((unsigned)h) << 16;
    return v.f;
}

// Region layout (128 rows x 32 k, 16B slots, 4 slots/row):
// q = row>>1, t = ((row&1)<<2)|slot, phys = q*8 + (t ^ (q&7)).
// Bijective; frag reads (16 rows x 4 slots) hit all 32 banks conflict-free.
__device__ __forceinline__ int swz(int row, int slot) {
    int q = row >> 1;
    int t = ((row & 1) << 2) | slot;
    return q * 8 + (t ^ (q & 7));
}

// ---- weight prep: fp32 [2048][512] -> bf16 hi/lo, rows permuted so a
// block's 128 rows = 32 units x 4 gates (gate index in bits [4:5] of rp).
// input row = g*512 + u ; rp = (u>>5)*128 + ((u>>4)&1)*64 + g*16 + (u&15)
struct SplitSrc { const float* src[6]; };

__global__ __launch_bounds__(256) void split_weights(SplitSrc s, ushort* __restrict__ hi,
                                                     ushort* __restrict__ lo) {
    int row = blockIdx.x;             // g*512 + u
    int j = blockIdx.y;               // matrix index
    int g = row >> 9, u = row & 511;
    int rp = (u >> 5) * 128 + ((u >> 4) & 1) * 64 + g * 16 + (u & 15);
    const float* S = s.src[j] + (size_t)row * HDIM;
    ushort* H = hi + ((size_t)j * 2048 + rp) * HDIM;
    ushort* L = lo + ((size_t)j * 2048 + rp) * HDIM;
    for (int k = threadIdx.x; k < HDIM; k += 256) {
        float w = S[k];
        ushort hb = f2bf(w);
        H[k] = hb;
        L[k] = f2bf(w - bf2f(hb));
    }
}

// ---- cell descriptor (one LSTM cell = one 2048x2048xK GEMM + gates) ----
struct CellDesc {
    const ushort *A1h, *A1l, *W1h, *W1l;
    const ushort *A2h, *A2l, *W2h, *W2l;
    const float *x; const float *Wx;
    const float *bih, *bhh;
    float* c; ushort *hh; ushort *hl;
    int np, xs, Kx;
};

// ---- fused LSTM cell(s): blocks [0,256) run dA, [256,512) run dB ----
// Block tile 128m x 128n (32 units x 4 gates), 4 waves 2x2, wave tile 64x64
// = 4 m-frags x 4 gate-frags of mfma_f32_16x16x32_bf16, 3-product split.
__global__ __launch_bounds__(256, 2) void lstm_cells(CellDesc dA, CellDesc dB) {
    // 2 buffers x 32KB. Regions (ushort offs): A_hi @0, A_lo @4096,
    // B_hi @8192, B_lo @12288; each 512 slots x 16B, swizzled.
    __shared__ __align__(16) ushort lds[2 * 16384];

    const CellDesc d = (blockIdx.x >> 8) ? dB : dA;

    const int tid = threadIdx.x;
    const int w = tid >> 6, l = tid & 63;
    const int wm = w >> 1, wn = w & 1;
    const int lrow = l & 15, lk = l >> 4;

    // XCD-chunked bijective swizzle within each cell's 256 blocks
    int id = blockIdx.x & 255;
    int xcd = id & 7, rr = id >> 3;
    int bx = (xcd & 3) * 4 + (rr & 3);
    int by = (xcd >> 2) * 8 + (rr >> 2);
    const int m0 = by * 128;
    const int n0 = bx * 128;
    const int u  = bx * 32 + wn * 16 + lrow;   // global hidden unit

    f32x4 acc[4][4];   // [m-frag][gate]

    // ---- bias + tiny-K x prologue FIRST (their vmem waits must not drain
    // the staging queue issued below) ----
    #pragma unroll
    for (int g = 0; g < 4; ++g) {
        float b = d.bih[g * HDIM + u] + d.bhh[g * HDIM + u];
        f32x4 bv = {b, b, b, b};
        #pragma unroll
        for (int fm = 0; fm < 4; ++fm) acc[fm][g] = bv;
    }
    if (d.Kx > 0) {
        for (int kx = 0; kx < d.Kx; ++kx) {
            float wv[4];
            #pragma unroll
            for (int g = 0; g < 4; ++g) wv[g] = d.Wx[(size_t)(g * HDIM + u) * d.Kx + kx];
            #pragma unroll
            for (int fm = 0; fm < 4; ++fm)
                #pragma unroll
                for (int r = 0; r < 4; ++r) {
                    int m = m0 + wm * 64 + fm * 16 + lk * 4 + r;
                    float xv = d.x[(size_t)m * d.xs + kx];
                    #pragma unroll
                    for (int g = 0; g < 4; ++g) acc[fm][g][r] += xv * wv[g];
                }
        }
    }

    // ---- staging: 16 global_load_lds (16B) per wave per chunk ----
    auto STAGE = [&](int t) {
        int buf = t & 1;
        int p = t >> 4;                 // 16 chunks per (A,W) pair
        int kc = (t & 15) * 32;
        const ushort* Ah = p ? d.A2h : d.A1h;
        const ushort* Al = p ? d.A2l : d.A1l;
        const ushort* Bh = p ? d.W2h : d.W1h;
        const ushort* Bl = p ? d.W2l : d.W1l;
        ushort* base = &lds[buf * 16384];
        #pragma unroll
        for (int it = 0; it < 2; ++it) {
            int db = (w * 2 + it) * 64;       // wave-uniform dest slot base
            int dd = db + l;                  // this lane's dest slot
            int q = dd >> 3, tp = dd & 7;
            int tl = tp ^ (q & 7);            // inverse swizzle -> logical
            int r = (q << 1) | (tl >> 2);
            int s = tl & 3;
            size_t go = (size_t)r * HDIM + kc + s * 8;
            __builtin_amdgcn_global_load_lds(AS1(Ah + (size_t)m0 * HDIM + go),
                                             AS3(base + db * 8), 16, 0, 0);
            __builtin_amdgcn_global_load_lds(AS1(Al + (size_t)m0 * HDIM + go),
                                             AS3(base + 4096 + db * 8), 16, 0, 0);
            __builtin_amdgcn_global_load_lds(AS1(Bh + (size_t)n0 * HDIM + go),
                                             AS3(base + 8192 + db * 8), 16, 0, 0);
            __builtin_amdgcn_global_load_lds(AS1(Bl + (size_t)n0 * HDIM + go),
                                             AS3(base + 12288 + db * 8), 16, 0, 0);
        }
    };

    const int nch = d.np * 16;
    STAGE(0);

    // ---- main loop: one __syncthreads per chunk (drains vmcnt+lgkm);
    // stage t+1 into the other buffer while computing t. Cross-block TLP
    // (2 blocks/CU) hides the drain. ----
    for (int t = 0; t < nch; ++t) {
        __syncthreads();                 // STAGE(t) visible; prev reads done
        if (t + 1 < nch) STAGE(t + 1);
        ushort* base = &lds[(t & 1) * 16384];
        short8 ah[4], al[4], bh[4], bl[4];
        #pragma unroll
        for (int fm = 0; fm < 4; ++fm) {
            int row = wm * 64 + fm * 16 + lrow;
            int off = swz(row, lk) * 8;
            ah[fm] = *(const short8*)(base + off);
            al[fm] = *(const short8*)(base + 4096 + off);
        }
        #pragma unroll
        for (int g = 0; g < 4; ++g) {
            int row = wn * 64 + g * 16 + lrow;
            int off = swz(row, lk) * 8;
            bh[g] = *(const short8*)(base + 8192 + off);
            bl[g] = *(const short8*)(base + 12288 + off);
        }
        #pragma unroll
        for (int fm = 0; fm < 4; ++fm)
            #pragma unroll
            for (int g = 0; g < 4; ++g)
                acc[fm][g] = __builtin_amdgcn_mfma_f32_16x16x32_bf16(
                    ah[fm], bh[g], acc[fm][g], 0, 0, 0);
        #pragma unroll
        for (int fm = 0; fm < 4; ++fm)
            #pragma unroll
            for (int g = 0; g < 4; ++g)
                acc[fm][g] = __builtin_amdgcn_mfma_f32_16x16x32_bf16(
                    al[fm], bh[g], acc[fm][g], 0, 0, 0);
        #pragma unroll
        for (int fm = 0; fm < 4; ++fm)
            #pragma unroll
            for (int g = 0; g < 4; ++g)
                acc[fm][g] = __builtin_amdgcn_mfma_f32_16x16x32_bf16(
                    ah[fm], bl[g], acc[fm][g], 0, 0, 0);
    }

    // ---- epilogue: gates + state update. Thread owns 16 rows x 1 unit. ----
    #pragma unroll
    for (int fm = 0; fm < 4; ++fm)
        #pragma unroll
        for (int r = 0; r < 4; ++r) {
            int m = m0 + wm * 64 + fm * 16 + lk * 4 + r;
            size_t idx = (size_t)m * HDIM + u;
            float zi = acc[fm][0][r], zf = acc[fm][1][r];
            float zg = acc[fm][2][r], zo = acc[fm][3][r];
            float ig = 1.f / (1.f + __expf(-zi));
            float fg = 1.f / (1.f + __expf(-zf));
            float gg = 2.f / (1.f + __expf(-2.f * zg)) - 1.f;
            float og = 1.f / (1.f + __expf(-zo));
            float cn = fg * d.c[idx] + ig * gg;
            float hn = og * (2.f / (1.f + __expf(-2.f * cn)) - 1.f);
            d.c[idx] = cn;
            ushort hb = f2bf(hn);
            d.hh[idx] = hb;
            d.hl[idx] = f2bf(hn - bf2f(hb));
        }
}

// ---- output head: pred = (h_hi+h_lo) @ out_W^T + out_b, one wave per row ----
__global__ __launch_bounds__(256) void head_kernel(
    const ushort* __restrict__ hhi, const ushort* __restrict__ hlo,
    const float* __restrict__ Wout, const float* __restrict__ bout,
    float* __restrict__ out, float* __restrict__ xbuf, int t)
{
    int wave = (blockIdx.x * 256 + threadIdx.x) >> 6;
    int lane = threadIdx.x & 63;
    const ushort* hr = hhi + (size_t)wave * HDIM;
    const ushort* lr = hlo + (size_t)wave * HDIM;
    float s0 = 0.f, s1 = 0.f;
    #pragma unroll
    for (int k = lane; k < HDIM; k += 64) {
        float hv = bf2f(hr[k]) + bf2f(lr[k]);
        s0 += hv * Wout[k];
        s1 += hv * Wout[HDIM + k];
    }
    #pragma unroll
    for (int off = 32; off > 0; off >>= 1) {
        s0 += __shfl_down(s0, off);
        s1 += __shfl_down(s1, off);
    }
    if (lane == 0) {
        float p0 = s0 + bout[0], p1 = s1 + bout[1];
        out[(size_t)wave * (T_FUT * 2) + t * 2 + 0] = p0;
        out[(size_t)wave * (T_FUT * 2) + t * 2 + 1] = p1;
        xbuf[wave * 2 + 0] = p0;
        xbuf[wave * 2 + 1] = p1;
    }
}

extern "C" void kernel_launch(void* const* d_in, const int* in_sizes, int n_in,
                              void* d_out, int out_size, void* d_ws, size_t ws_size,
                              hipStream_t stream) {
    const float* history = (const float*)d_in[0];
    const float* eWih0 = (const float*)d_in[2];
    const float* eWhh0 = (const float*)d_in[3];
    const float* ebih0 = (const float*)d_in[4];
    const float* ebhh0 = (const float*)d_in[5];
    const float* eWih1 = (const float*)d_in[6];
    const float* eWhh1 = (const float*)d_in[7];
    const float* ebih1 = (const float*)d_in[8];
    const float* ebhh1 = (const float*)d_in[9];
    const float* dWih0 = (const float*)d_in[10];
    const float* dWhh0 = (const float*)d_in[11];
    const float* dbih0 = (const float*)d_in[12];
    const float* dbhh0 = (const float*)d_in[13];
    const float* dWih1 = (const float*)d_in[14];
    const float* dWhh1 = (const float*)d_in[15];
    const float* dbih1 = (const float*)d_in[16];
    const float* dbhh1 = (const float*)d_in[17];
    const float* outW  = (const float*)d_in[18];
    const float* outb  = (const float*)d_in[19];
    float* out = (float*)d_out;

    // ---- workspace layout ----
    const size_t M = (size_t)2048 * 512;
    ushort* whi = (ushort*)d_ws;           // 6 split-hi weight matrices
    ushort* wlo = whi + 6 * M;             // 6 split-lo
    ushort* hb  = wlo + 6 * M;             // 8 h buffers (hi/lo x 2 layers x dbuf)
    float*  c0  = (float*)(hb + 8 * M);
    float*  c1  = c0 + M;
    float*  xbuf = c1 + M;                 // [B,2] decoder feedback

    ushort* h0a_hi = hb + 0 * M; ushort* h0a_lo = hb + 1 * M;
    ushort* h0b_hi = hb + 2 * M; ushort* h0b_lo = hb + 3 * M;
    ushort* h1a_hi = hb + 4 * M; ushort* h1a_lo = hb + 5 * M;
    ushort* h1b_hi = hb + 6 * M; ushort* h1b_lo = hb + 7 * M;

    hipMemsetAsync(h0a_hi, 0, 2 * M * sizeof(ushort), stream);
    hipMemsetAsync(h1a_hi, 0, 2 * M * sizeof(ushort), stream);
    hipMemsetAsync(c0, 0, 2 * M * sizeof(float), stream);
    hipMemsetAsync(xbuf, 0, BDIM * 2 * sizeof(float), stream);

    SplitSrc ss;
    ss.src[0] = eWhh0; ss.src[1] = eWih1; ss.src[2] = eWhh1;
    ss.src[3] = dWhh0; ss.src[4] = dWih1; ss.src[5] = dWhh1;
    split_weights<<<dim3(2048, 6), 256, 0, stream>>>(ss, whi, wlo);

    #define WHI(j) (whi + (size_t)(j) * M)
    #define WLO(j) (wlo + (size_t)(j) * M)

    // per-step buffer parity
    auto H0R_HI = [&](int s){ return (s & 1) ? h0b_hi : h0a_hi; };
    auto H0R_LO = [&](int s){ return (s & 1) ? h0b_lo : h0a_lo; };
    auto H0W_HI = [&](int s){ return (s & 1) ? h0a_hi : h0b_hi; };
    auto H0W_LO = [&](int s){ return (s & 1) ? h0a_lo : h0b_lo; };
    auto H1R_HI = [&](int s){ return (s & 1) ? h1b_hi : h1a_hi; };
    auto H1R_LO = [&](int s){ return (s & 1) ? h1b_lo : h1a_lo; };
    auto H1W_HI = [&](int s){ return (s & 1) ? h1a_hi : h1b_hi; };
    auto H1W_LO = [&](int s){ return (s & 1) ? h1a_lo : h1b_lo; };

    auto mkL0enc = [&](int s) {
        CellDesc d{};
        d.A1h = H0R_HI(s); d.A1l = H0R_LO(s); d.W1h = WHI(0); d.W1l = WLO(0);
        d.np = 1; d.x = history + s * 5; d.xs = T_HIST * 5; d.Kx = 5; d.Wx = eWih0;
        d.bih = ebih0; d.bhh = ebhh0; d.c = c0; d.hh = H0W_HI(s); d.hl = H0W_LO(s);
        return d;
    };
    auto mkL1enc = [&](int s) {
        CellDesc d{};
        d.A1h = H0W_HI(s); d.A1l = H0W_LO(s); d.W1h = WHI(1); d.W1l = WLO(1);
        d.A2h = H1R_HI(s); d.A2l = H1R_LO(s); d.W2h = WHI(2); d.W2l = WLO(2);
        d.np = 2; d.Kx = 0; d.xs = 0;
        d.bih = ebih1; d.bhh = ebhh1; d.c = c1; d.hh = H1W_HI(s); d.hl = H1W_LO(s);
        return d;
    };
    auto mkD0 = [&](int s) {
        CellDesc d{};
        d.A1h = H0R_HI(s); d.A1l = H0R_LO(s); d.W1h = WHI(3); d.W1l = WLO(3);
        d.np = 1; d.x = xbuf; d.xs = 2; d.Kx = 2; d.Wx = dWih0;
        d.bih = dbih0; d.bhh = dbhh0; d.c = c0; d.hh = H0W_HI(s); d.hl = H0W_LO(s);
        return d;
    };
    auto mkD1 = [&](int s) {
        CellDesc d{};
        d.A1h = H0W_HI(s); d.A1l = H0W_LO(s); d.W1h = WHI(4); d.W1l = WLO(4);
        d.A2h = H1R_HI(s); d.A2l = H1R_LO(s); d.W2h = WHI(5); d.W2l = WLO(5);
        d.np = 2; d.Kx = 0; d.xs = 0;
        d.bih = dbih1; d.bhh = dbhh1; d.c = c1; d.hh = H1W_HI(s); d.hl = H1W_LO(s);
        return d;
    };

    dim3 blk(256);

    // encoder step 0, layer 0 alone
    {
        CellDesc d = mkL0enc(0);
        lstm_cells<<<256, blk, 0, stream>>>(d, d);
    }
    // paired: [L1(s) || L0(s+1)], with the last pair feeding the decoder
    for (int s = 0; s < T_HIST; ++s) {
        CellDesc dL1 = mkL1enc(s);
        CellDesc dNx = (s + 1 < T_HIST) ? mkL0enc(s + 1) : mkD0(T_HIST);
        lstm_cells<<<512, blk, 0, stream>>>(dL1, dNx);
    }
    // decoder: D1(s) -> head(s) -> D0(s+1)
    for (int s = T_HIST; s < T_HIST + T_FUT; ++s) {
        CellDesc d1 = mkD1(s);
        lstm_cells<<<256, blk, 0, stream>>>(d1, d1);
        head_kernel<<<512, blk, 0, stream>>>(H1W_HI(s), H1W_LO(s), outW, outb,
                                             out, xbuf, s - T_HIST);
        if (s + 1 < T_HIST + T_FUT) {
            CellDesc d0 = mkD0(s + 1);
            lstm_cells<<<256, blk, 0, stream>>>(d0, d0);
        }
    }
    #undef WHI
    #undef WLO
}